// Round 1
// baseline (61.451 us; speedup 1.0000x reference)
//
#include <hip/hip_runtime.h>
#include <stdint.h>

#define D 128
#define ROWS 32
#define NTHREADS 512
#define G 16
#define JPL 8  // j's per lane = D/G

__device__ __forceinline__ uint16_t f2bf(float f) {
  uint32_t u = __float_as_uint(f);
  u += 0x7fffu + ((u >> 16) & 1u);  // round-to-nearest-even
  return (uint16_t)(u >> 16);
}

__global__ __launch_bounds__(NTHREADS, 1)
void iaf_kernel(const float* __restrict__ x, const float* __restrict__ W1,
                const float* __restrict__ b1, const float* __restrict__ Wmu,
                const float* __restrict__ bmu, const float* __restrict__ Wls,
                const float* __restrict__ bls, float* __restrict__ out, int B) {
  __shared__ uint32_t wml[D][D];   // lo16 = bf16(Wmu[i][j], masked j<i), hi16 = bf16(Wls[i][j])
  __shared__ uint16_t w1t[D][D];   // [i][j] = bf16(W1[j][i]) masked (nonzero only j>i)
  __shared__ float xs[ROWS][D];
  __shared__ float zs[ROWS][D];
  __shared__ float bmus[D];
  __shared__ float blss[D];

  const int tid = threadIdx.x;
  const int r0 = blockIdx.x * ROWS;

  // ---- stage weights (masks baked in) ----
  for (int idx = tid; idx < D * D; idx += NTHREADS) {
    const int i = idx >> 7, j = idx & (D - 1);
    const float wmu = (j < i) ? Wmu[idx] : 0.f;
    const float wls = (j < i) ? Wls[idx] : 0.f;
    wml[i][j] = ((uint32_t)f2bf(wls) << 16) | (uint32_t)f2bf(wmu);
    const float w1 = (j > i) ? W1[j * D + i] : 0.f;
    w1t[i][j] = f2bf(w1);
  }
  if (tid < D) { bmus[tid] = bmu[tid]; blss[tid] = bls[tid]; }
  // ---- stage x rows (coalesced) ----
  for (int idx = tid; idx < ROWS * D; idx += NTHREADS) {
    xs[idx >> 7][idx & (D - 1)] = x[(size_t)r0 * D + idx];
  }
  __syncthreads();

  const int g   = tid / G;        // row within block (0..31)
  const int sub = tid & (G - 1);  // lane within 16-lane group
  const int j0  = sub * JPL;

  float a[JPL];
#pragma unroll
  for (int t = 0; t < JPL; ++t) a[t] = b1[j0 + t];
  float ldj = 0.f;

  for (int i = 0; i < D; ++i) {
    const uint4 wa  = *reinterpret_cast<const uint4*>(&wml[i][j0]);
    const uint4 wb  = *reinterpret_cast<const uint4*>(&wml[i][j0 + 4]);
    const uint4 w1v = *reinterpret_cast<const uint4*>(&w1t[i][j0]);
    const float xi  = xs[g][i];

    float h[JPL];
#pragma unroll
    for (int t = 0; t < JPL; ++t) h[t] = fmaxf(a[t], 0.f);

    const uint32_t ws[8] = {wa.x, wa.y, wa.z, wa.w, wb.x, wb.y, wb.z, wb.w};
    float mu = 0.f, ls = 0.f;
#pragma unroll
    for (int t = 0; t < JPL; ++t) {
      const float wmuf = __uint_as_float(ws[t] << 16);
      const float wlsf = __uint_as_float(ws[t] & 0xffff0000u);
      mu = fmaf(h[t], wmuf, mu);
      ls = fmaf(h[t], wlsf, ls);
    }
#pragma unroll
    for (int m = 1; m < G; m <<= 1) {
      mu += __shfl_xor(mu, m, G);
      ls += __shfl_xor(ls, m, G);
    }
    mu += bmus[i];
    ls += blss[i];

    const float zi = fmaf(xi, __expf(ls), mu);
    ldj += ls;
    if (sub == 0) zs[g][i] = zi;

    const uint32_t w1s[4] = {w1v.x, w1v.y, w1v.z, w1v.w};
#pragma unroll
    for (int t = 0; t < 4; ++t) {
      const float wlo = __uint_as_float(w1s[t] << 16);
      const float whi = __uint_as_float(w1s[t] & 0xffff0000u);
      a[2 * t]     = fmaf(zi, wlo, a[2 * t]);
      a[2 * t + 1] = fmaf(zi, whi, a[2 * t + 1]);
    }
  }

  __syncthreads();
  // ---- write z (coalesced) ----
  for (int idx = tid; idx < ROWS * D; idx += NTHREADS) {
    out[(size_t)r0 * D + idx] = zs[idx >> 7][idx & (D - 1)];
  }
  // ---- write ldj ----
  if (sub == 0) out[(size_t)B * D + r0 + g] = ldj;
}

extern "C" void kernel_launch(void* const* d_in, const int* in_sizes, int n_in,
                              void* d_out, int out_size, void* d_ws, size_t ws_size,
                              hipStream_t stream) {
  const float* x   = (const float*)d_in[0];
  const float* W1  = (const float*)d_in[1];
  const float* b1  = (const float*)d_in[2];
  const float* Wmu = (const float*)d_in[3];
  const float* bmu = (const float*)d_in[4];
  const float* Wls = (const float*)d_in[5];
  const float* bls = (const float*)d_in[6];
  float* out = (float*)d_out;

  const int B = in_sizes[0] / D;        // 8192
  const int grid = (B + ROWS - 1) / ROWS;  // 256
  iaf_kernel<<<grid, NTHREADS, 0, stream>>>(x, W1, b1, Wmu, bmu, Wls, bls, out, B);
}